// Round 9
// baseline (1152.431 us; speedup 1.0000x reference)
//
#include <hip/hip_runtime.h>

// 2-layer LSTM, B=512, T=1024, H=64 (tf LSTMCell, gates i,j,f,o, forget bias 1.0)
// One block (576 thr = 9 waves) per batch element. Split-K over wave halves:
// wave w owns gate columns [32w,32w+32), lanes 0-31 k=0..32 (x+bias), lanes
// 32-63 k=33..64; halves combined with one __shfl_xor(p,32). One barrier/step.
//
// Rounds 4-8 lesson: W1 loads are invariant-loads -> legal remat candidates;
// the scheduler re-executes all 33 per t-iteration chasing 8-waves/EU
// occupancy (VGPR_Count 40-48), leaving the kernel L2-BW bound re-reading
// 34 MB/step of weights. Countermeasures:
//   (a) w[j] = load * one, one = fmaf(b2[0],0,1) == 1.0f at runtime but not
//       foldable without fast-math -> loop consumes a non-rematerializable mul.
//   (b) amdgpu_waves_per_eu(4,5): pressure budget ~102 VGPR (grid only
//       supplies 4.5 waves/SIMD, so >5/EU occupancy is worthless anyway).

#define TT 1024

__device__ __forceinline__ float fsig(float x) {
    return __builtin_amdgcn_rcpf(1.f + __expf(-x));
}
__device__ __forceinline__ float ftanh(float x) {
    return 1.f - 2.f * __builtin_amdgcn_rcpf(1.f + __expf(2.f * x));
}

template <int Ctrl, int Rmask>
__device__ __forceinline__ float dpp_add(float x) {
    int t = __builtin_amdgcn_update_dpp(0, __float_as_int(x), Ctrl, Rmask, 0xf, true);
    return x + __int_as_float(t);
}
// Sum across 64 lanes; result valid in lane 63. 6 dependent VALU ops.
__device__ __forceinline__ float wave_sum64(float x) {
    x = dpp_add<0x111, 0xf>(x); // row_shr:1
    x = dpp_add<0x112, 0xf>(x); // row_shr:2
    x = dpp_add<0x114, 0xf>(x); // row_shr:4
    x = dpp_add<0x118, 0xf>(x); // row_shr:8
    x = dpp_add<0x142, 0xa>(x); // row_bcast:15
    x = dpp_add<0x143, 0xc>(x); // row_bcast:31 -> lane63 = total
    return x;
}

__global__ __launch_bounds__(576)
__attribute__((amdgpu_waves_per_eu(4, 5)))
void lstm2_kernel(
    const float* __restrict__ x,    // [B, T]
    const float* __restrict__ W1,   // [65, 256]; row0 = x, rows 1..64 = h1
    const float* __restrict__ b1,   // [256]
    const float* __restrict__ W2,   // [65, 4]; rows 0..63 = h1, row 64 = h2
    const float* __restrict__ b2,   // [4]
    float* __restrict__ y)          // [B, T]
{
    __shared__ __align__(16) float xs[TT];
    __shared__ __align__(16) float h1s[64];
    __shared__ __align__(16) float gs[2][4][64];  // parity double-buffered gates
    __shared__ float dbuf[2][4];                  // parity-buffered layer-2 dots

    const int tid  = threadIdx.x;
    const int b    = blockIdx.x;
    const int lane = tid & 63;
    const int cw   = tid >> 6;        // 0..7 compute waves, 8 = layer-2 wave
    const int half = lane >> 5;       // split-k half within the wave
    const int l31  = lane & 31;
    const int col  = (cw << 5) | l31; // gate column (cw<8)
    const int g    = cw >> 1;         // gate id (wave-uniform)

    // stage x row into LDS (coalesced float4)
    if (tid < 256) {
        ((float4*)xs)[tid] = ((const float4*)(x + (size_t)b * TT))[tid];
    }

    // runtime 1.0f the compiler cannot fold (b2[0] could be NaN/inf for all
    // it knows; actually b2 = zeros -> fmaf(0,0,1) = 1.0f exactly)
    const float one = fmaf(b2[0], 0.f, 1.f);

    // per-thread layer-1 weights: 33 floats (half a column) in registers.
    // The *one multiply makes each w[j] a non-rematerializable mul result.
    float w[33];
    float bias = 0.f, w2g = 0.f;
    if (cw < 8) {
        if (half == 0) {
            w[0] = W1[col] * one;          // x-row weight
            bias = b1[col];
#pragma unroll
            for (int j = 1; j <= 32; ++j) w[j] = W1[j * 256 + col] * one;        // rows 1..32
        } else {
            w[0] = 0.f;                    // no x term, no bias in upper half
#pragma unroll
            for (int j = 1; j <= 32; ++j) w[j] = W1[(32 + j) * 256 + col] * one; // rows 33..64
        }
    }
    if (cw < 4) w2g = W2[lane * 4 + cw];   // W2[lane][cw] for the DPP dot

    // layer-2 scalar constants
    const float w2h0 = W2[256], w2h1 = W2[257], w2h2 = W2[258], w2h3 = W2[259];
    const float b20 = b2[0], b21 = b2[1], b22 = b2[2], b23 = b2[3];

    float c1 = 0.f;              // replicated cell state of hidden unit `lane`
    float c2 = 0.f, h2 = 0.f;    // wave-8 layer-2 state

    if (tid < 64) h1s[tid] = 0.f;
    __syncthreads();

    float* yrow = y + (size_t)b * TT;
    const int hbase = half << 3;   // float4 base index into h1s: 0 or 8

    for (int t = 0; t < TT; ++t) {
        const int par = t & 1;
        if (cw < 8) {
            // ---- phase 1: half-column matvec (33 FMA) ----
            const float xt = xs[t];
            float a0 = fmaf(xt, w[0], bias), a1 = 0.f, a2 = 0.f, a3 = 0.f;
#pragma unroll
            for (int q = 0; q < 8; ++q) {
                float4 h4 = ((const float4*)h1s)[hbase + q];  // 2-addr broadcast (free)
                a0 = fmaf(h4.x, w[1 + 4*q], a0);
                a1 = fmaf(h4.y, w[2 + 4*q], a1);
                a2 = fmaf(h4.z, w[3 + 4*q], a2);
                a3 = fmaf(h4.w, w[4 + 4*q], a3);
            }
            float p = (a0 + a1) + (a2 + a3);
            p += __shfl_xor(p, 32);          // combine the two k-halves in-wave
            float act;
            if (g == 1)      act = ftanh(p);          // j
            else if (g == 2) act = fsig(p + 1.f);     // f (+forget bias)
            else             act = fsig(p);           // i, o
            if (half == 0) gs[par][g][(cw & 1) * 32 + l31] = act;
        }
        __syncthreads();   // the ONLY barrier per step
        if (cw < 8) {
            // ---- phase 2: replicated cell update (identical in waves 0-7) ----
            const float i_ = gs[par][0][lane], j_ = gs[par][1][lane];
            const float f_ = gs[par][2][lane], o_ = gs[par][3][lane];
            c1 = fmaf(c1, f_, i_ * j_);
            const float h1 = ftanh(c1) * o_;
            h1s[lane] = h1;                 // benign same-value multi-wave write
            if (cw < 4) {                   // layer-2 dot for gate cw
                float p = wave_sum64(h1 * w2g);
                if (lane == 63) dbuf[par][cw] = p;
            }
        } else if (t > 0 && lane == 0) {
            // ---- wave 8: layer-2 recurrence for step t-1 ----
            const int pp = par ^ 1;
            const float d0 = dbuf[pp][0], d1 = dbuf[pp][1];
            const float d2 = dbuf[pp][2], d3 = dbuf[pp][3];
            const float i2 = fsig (fmaf(h2, w2h0, d0) + b20);
            const float j2 = ftanh(fmaf(h2, w2h1, d1) + b21);
            const float f2 = fsig (fmaf(h2, w2h2, d2) + b22 + 1.f);
            const float o2 = fsig (fmaf(h2, w2h3, d3) + b23);
            c2 = fmaf(c2, f2, i2 * j2);
            h2 = ftanh(c2) * o2;
            yrow[t - 1] = h2;
        }
    }
    __syncthreads();
    if (cw == 8 && lane == 0) {   // final layer-2 step (t = TT-1)
        const int pp = (TT - 1) & 1;
        const float d0 = dbuf[pp][0], d1 = dbuf[pp][1];
        const float d2 = dbuf[pp][2], d3 = dbuf[pp][3];
        const float i2 = fsig (fmaf(h2, w2h0, d0) + b20);
        const float j2 = ftanh(fmaf(h2, w2h1, d1) + b21);
        const float f2 = fsig (fmaf(h2, w2h2, d2) + b22 + 1.f);
        const float o2 = fsig (fmaf(h2, w2h3, d3) + b23);
        c2 = fmaf(c2, f2, i2 * j2);
        h2 = ftanh(c2) * o2;
        yrow[TT - 1] = h2;
    }
}

extern "C" void kernel_launch(void* const* d_in, const int* in_sizes, int n_in,
                              void* d_out, int out_size, void* d_ws, size_t ws_size,
                              hipStream_t stream) {
    const float* x  = (const float*)d_in[0];
    const float* W1 = (const float*)d_in[1];
    const float* b1 = (const float*)d_in[2];
    const float* W2 = (const float*)d_in[3];
    const float* b2 = (const float*)d_in[4];
    float* y = (float*)d_out;
    lstm2_kernel<<<512, 576, 0, stream>>>(x, W1, b1, W2, b2, y);
}

// Round 10
// 1047.997 us; speedup vs baseline: 1.0997x; 1.0997x over previous
//
#include <hip/hip_runtime.h>

// 2-layer LSTM, B=512, T=1024, H=64 (tf LSTMCell, gates i,j,f,o, forget bias 1.0)
// One block (1024 thr = 16 waves) per batch element, SPLIT-K=4 inside the wave:
//   wave w owns gate columns [16w, 16w+16) (gate g = w>>2, wave-uniform);
//   lane quadrant q = lane>>4 owns h-rows 16q+1..16q+16 (q0 also x-row+bias);
//   partials combined with shfl_xor(16) + shfl_xor(32).
// Per-thread weights: 17 floats -> natural VGPR need ~42, UNDER the 64-VGPR /
// 8-waves-per-EU budget the scheduler insists on (rounds 4-9: 33-65 weights
// always got rematerialized into the t-loop -> L1/L2-BW bound at ~1800cy/step;
// every RA-override knob failed). At 1024 thr/block, max occupancy = exactly
// our 2 blocks/CU -> compiler's goal and ours coincide.
// Cell update replicated in all 16 waves (bit-identical) -> 1 barrier/step.
// Layer-2 dots via DPP wave reduction on waves 0-3; serial layer-2 recurrence
// on wave 15 lane 0, one step behind (parity-buffered dbuf).

#define TT 1024

__device__ __forceinline__ float fsig(float x) {
    return __builtin_amdgcn_rcpf(1.f + __expf(-x));
}
__device__ __forceinline__ float ftanh(float x) {
    return 1.f - 2.f * __builtin_amdgcn_rcpf(1.f + __expf(2.f * x));
}

template <int Ctrl, int Rmask>
__device__ __forceinline__ float dpp_add(float x) {
    int t = __builtin_amdgcn_update_dpp(0, __float_as_int(x), Ctrl, Rmask, 0xf, true);
    return x + __int_as_float(t);
}
// Sum across 64 lanes; result valid in lane 63. 6 dependent VALU ops.
__device__ __forceinline__ float wave_sum64(float x) {
    x = dpp_add<0x111, 0xf>(x); // row_shr:1
    x = dpp_add<0x112, 0xf>(x); // row_shr:2
    x = dpp_add<0x114, 0xf>(x); // row_shr:4
    x = dpp_add<0x118, 0xf>(x); // row_shr:8
    x = dpp_add<0x142, 0xa>(x); // row_bcast:15
    x = dpp_add<0x143, 0xc>(x); // row_bcast:31 -> lane63 = total
    return x;
}

__global__ __launch_bounds__(1024) void lstm2_kernel(
    const float* __restrict__ x,    // [B, T]
    const float* __restrict__ W1,   // [65, 256]; row0 = x, rows 1..64 = h1
    const float* __restrict__ b1,   // [256]
    const float* __restrict__ W2,   // [65, 4]; rows 0..63 = h1, row 64 = h2
    const float* __restrict__ b2,   // [4]
    float* __restrict__ y)          // [B, T]
{
    __shared__ __align__(16) float xs[TT];
    __shared__ __align__(16) float h1s[64];
    __shared__ __align__(16) float gs[2][4][64];  // parity double-buffered gates
    __shared__ float dbuf[2][4];                  // parity-buffered layer-2 dots

    const int tid  = threadIdx.x;
    const int b    = blockIdx.x;
    const int lane = tid & 63;
    const int wv   = tid >> 6;          // wave id 0..15
    const int q    = lane >> 4;         // k-quadrant 0..3
    const int l15  = lane & 15;
    const int col  = (wv << 4) | l15;   // gate column 0..255
    const int g    = wv >> 2;           // gate id (wave-uniform)

    // stage x row into LDS (coalesced float4)
    if (tid < 256) {
        ((float4*)xs)[tid] = ((const float4*)(x + (size_t)b * TT))[tid];
    }

    // per-thread layer-1 weights: 17 floats (quarter column) in registers
    float w[17];
    float bias = 0.f;
    if (q == 0) { w[0] = W1[col]; bias = b1[col]; }
    else        { w[0] = 0.f; }
#pragma unroll
    for (int j = 1; j <= 16; ++j) w[j] = W1[(16 * q + j) * 256 + col];

    float w2g = 0.f;
    if (wv < 4) w2g = W2[lane * 4 + wv];   // W2[lane][wv] for the DPP dot

    // layer-2 scalar constants (wave 15 uses them)
    const float w2h0 = W2[256], w2h1 = W2[257], w2h2 = W2[258], w2h3 = W2[259];
    const float b20 = b2[0], b21 = b2[1], b22 = b2[2], b23 = b2[3];

    float c1 = 0.f;              // replicated cell state of hidden unit `lane`
    float c2 = 0.f, h2 = 0.f;    // wave-15 layer-2 state

    if (tid < 64) h1s[tid] = 0.f;
    __syncthreads();

    float* yrow = y + (size_t)b * TT;
    const int hbase = q << 2;    // float4 base index into h1s: 4 per quadrant

    for (int t = 0; t < TT; ++t) {
        const int par = t & 1;
        // ---- phase 1: quarter-column matvec (17 FMA), all 16 waves ----
        const float xt = xs[t];
        float a0 = fmaf(xt, w[0], bias), a1 = 0.f, a2 = 0.f, a3 = 0.f;
#pragma unroll
        for (int jj = 0; jj < 4; ++jj) {
            float4 h4 = ((const float4*)h1s)[hbase + jj];  // 4-addr broadcast
            a0 = fmaf(h4.x, w[1 + 4*jj], a0);
            a1 = fmaf(h4.y, w[2 + 4*jj], a1);
            a2 = fmaf(h4.z, w[3 + 4*jj], a2);
            a3 = fmaf(h4.w, w[4 + 4*jj], a3);
        }
        float p = (a0 + a1) + (a2 + a3);
        p += __shfl_xor(p, 16);          // combine quadrants 0<->1, 2<->3
        p += __shfl_xor(p, 32);          // combine halves
        float act;
        if (g == 1)      act = ftanh(p);          // j
        else if (g == 2) act = fsig(p + 1.f);     // f (+forget bias)
        else             act = fsig(p);           // i, o
        if (q == 0) gs[par][g][((wv & 3) << 4) | l15] = act;

        __syncthreads();   // the ONLY barrier per step

        // ---- phase 2: replicated cell update (identical in all 16 waves) ----
        const float i_ = gs[par][0][lane], j_ = gs[par][1][lane];
        const float f_ = gs[par][2][lane], o_ = gs[par][3][lane];
        c1 = fmaf(c1, f_, i_ * j_);
        const float h1 = ftanh(c1) * o_;
        h1s[lane] = h1;                 // benign same-value multi-wave write
        if (wv < 4) {                   // layer-2 dot for gate wv
            float pd = wave_sum64(h1 * w2g);
            if (lane == 63) dbuf[par][wv] = pd;
        } else if (wv == 15 && t > 0 && lane == 0) {
            // ---- wave 15: layer-2 recurrence for step t-1 ----
            const int pp = par ^ 1;
            const float d0 = dbuf[pp][0], d1 = dbuf[pp][1];
            const float d2 = dbuf[pp][2], d3 = dbuf[pp][3];
            const float i2 = fsig (fmaf(h2, w2h0, d0) + b20);
            const float j2 = ftanh(fmaf(h2, w2h1, d1) + b21);
            const float f2 = fsig (fmaf(h2, w2h2, d2) + b22 + 1.f);
            const float o2 = fsig (fmaf(h2, w2h3, d3) + b23);
            c2 = fmaf(c2, f2, i2 * j2);
            h2 = ftanh(c2) * o2;
            yrow[t - 1] = h2;
        }
    }
    __syncthreads();
    if (wv == 15 && lane == 0) {   // final layer-2 step (t = TT-1)
        const int pp = (TT - 1) & 1;
        const float d0 = dbuf[pp][0], d1 = dbuf[pp][1];
        const float d2 = dbuf[pp][2], d3 = dbuf[pp][3];
        const float i2 = fsig (fmaf(h2, w2h0, d0) + b20);
        const float j2 = ftanh(fmaf(h2, w2h1, d1) + b21);
        const float f2 = fsig (fmaf(h2, w2h2, d2) + b22 + 1.f);
        const float o2 = fsig (fmaf(h2, w2h3, d3) + b23);
        c2 = fmaf(c2, f2, i2 * j2);
        h2 = ftanh(c2) * o2;
        yrow[TT - 1] = h2;
    }
}

extern "C" void kernel_launch(void* const* d_in, const int* in_sizes, int n_in,
                              void* d_out, int out_size, void* d_ws, size_t ws_size,
                              hipStream_t stream) {
    const float* x  = (const float*)d_in[0];
    const float* W1 = (const float*)d_in[1];
    const float* b1 = (const float*)d_in[2];
    const float* W2 = (const float*)d_in[3];
    const float* b2 = (const float*)d_in[4];
    float* y = (float*)d_out;
    lstm2_kernel<<<512, 1024, 0, stream>>>(x, W1, b1, W2, b2, y);
}

// Round 11
// 967.925 us; speedup vs baseline: 1.1906x; 1.0827x over previous
//
#include <hip/hip_runtime.h>

// 2-layer LSTM, B=512, T=1024, H=64 (tf LSTMCell, gates i,j,f,o, forget bias 1.0)
// One block (320 thr = 5 waves) per batch element. Wave g in 0..3 owns gate g,
// lane = column within gate (col = 64g + lane). Wave 4 = serial layer-2.
//
// Two structural fixes from rounds 4-10 evidence:
//  (1) Weights loaded with OPAQUE inline-asm global_load_dword: the backend
//      rematerialized ordinary invariant loads into the t-loop at every
//      footprint (65/33/17 per thread, VGPR_Count 24-48) regardless of
//      waves_per_eu hints -> kernel was L1/L2-BW bound re-streaming W1 every
//      step. Asm results cannot be remat'd or sunk; worst case they AGPR-
//      shuffle (2-cy VALU), still on-chip.
//  (2) h broadcast via v_readlane (register -> SGPR -> fmac src0) instead of
//      LDS: LDS h-reads cost an invariant ~65KB/block/step of LDS return BW
//      (~1.5k cy/step/CU) at any split-K. Phase-2 is replicated per wave, so
//      h for unit=lane already lives in a register of every wave.
// One barrier/step; gs parity-double-buffered; layer-2 runs one step behind.

#define TT 1024

__device__ __forceinline__ float fsig(float x) {
    return __builtin_amdgcn_rcpf(1.f + __expf(-x));
}
__device__ __forceinline__ float ftanh(float x) {
    return 1.f - 2.f * __builtin_amdgcn_rcpf(1.f + __expf(2.f * x));
}

template <int Ctrl, int Rmask>
__device__ __forceinline__ float dpp_add(float x) {
    int t = __builtin_amdgcn_update_dpp(0, __float_as_int(x), Ctrl, Rmask, 0xf, true);
    return x + __int_as_float(t);
}
// Sum across 64 lanes; result valid in lane 63. 6 dependent VALU ops.
__device__ __forceinline__ float wave_sum64(float x) {
    x = dpp_add<0x111, 0xf>(x); // row_shr:1
    x = dpp_add<0x112, 0xf>(x); // row_shr:2
    x = dpp_add<0x114, 0xf>(x); // row_shr:4
    x = dpp_add<0x118, 0xf>(x); // row_shr:8
    x = dpp_add<0x142, 0xa>(x); // row_bcast:15
    x = dpp_add<0x143, 0xc>(x); // row_bcast:31 -> lane63 = total
    return x;
}

// Opaque load: compiler cannot rematerialize/sink an asm instruction.
__device__ __forceinline__ float opaque_load(const float* p) {
    float r;
    asm volatile("global_load_dword %0, %1, off" : "=v"(r) : "v"(p));
    return r;
}

__device__ __forceinline__ float rl(float v, int k) {  // k must be constant
    return __int_as_float(__builtin_amdgcn_readlane(__float_as_int(v), k));
}

__global__ __launch_bounds__(320) void lstm2_kernel(
    const float* __restrict__ x,    // [B, T]
    const float* __restrict__ W1,   // [65, 256]; row0 = x, rows 1..64 = h1
    const float* __restrict__ b1,   // [256]
    const float* __restrict__ W2,   // [65, 4]; rows 0..63 = h1, row 64 = h2
    const float* __restrict__ b2,   // [4]
    float* __restrict__ y)          // [B, T]
{
    __shared__ __align__(16) float xs[TT];
    __shared__ __align__(16) float gs[2][4][64];  // parity double-buffered gates
    __shared__ float dbuf[2][4];                  // parity-buffered layer-2 dots

    const int tid  = threadIdx.x;
    const int b    = blockIdx.x;
    const int lane = tid & 63;
    const int g    = tid >> 6;      // 0..3 compute waves (= gate id), 4 = aux

    if (tid < 256) {
        ((float4*)xs)[tid] = ((const float4*)(x + (size_t)b * TT))[tid];
    }

    // ---- weights: 64 h-row weights + x-row + bias + W2 col, ALL opaque ----
    float w[64];
    float wx = 0.f, bias = 0.f, w2g = 0.f;
    if (g < 4) {
        const int col = (g << 6) | lane;
        wx   = opaque_load(W1 + col);
        bias = opaque_load(b1 + col);
        w2g  = opaque_load(W2 + lane * 4 + g);
#pragma unroll
        for (int k = 0; k < 64; ++k) {
            w[k] = opaque_load(W1 + (k + 1) * 256 + col);
        }
        asm volatile("s_waitcnt vmcnt(0)" ::: "memory");
    }

    // layer-2 scalar constants (uniform -> SGPRs; remat harmless)
    const float w2h0 = W2[256], w2h1 = W2[257], w2h2 = W2[258], w2h3 = W2[259];
    const float b20 = b2[0], b21 = b2[1], b22 = b2[2], b23 = b2[3];

    float c1 = 0.f, h1 = 0.f;    // replicated state of hidden unit `lane`
    float c2 = 0.f, h2 = 0.f;    // wave-4 layer-2 state

    __syncthreads();

    float* yrow = y + (size_t)b * TT;

    for (int t = 0; t < TT; ++t) {
        const int par = t & 1;
        if (g < 4) {
            // ---- phase 1: full column dot via readlane h-broadcast ----
            const float xt = xs[t];
            float a0 = fmaf(xt, wx, bias), a1 = 0.f, a2 = 0.f, a3 = 0.f;
#pragma unroll
            for (int k = 0; k < 16; ++k) {
                a0 = fmaf(rl(h1, 4 * k + 0), w[4 * k + 0], a0);
                a1 = fmaf(rl(h1, 4 * k + 1), w[4 * k + 1], a1);
                a2 = fmaf(rl(h1, 4 * k + 2), w[4 * k + 2], a2);
                a3 = fmaf(rl(h1, 4 * k + 3), w[4 * k + 3], a3);
            }
            float p = (a0 + a1) + (a2 + a3);
            float act;
            if (g == 1)      act = ftanh(p);          // j
            else if (g == 2) act = fsig(p + 1.f);     // f (+forget bias)
            else             act = fsig(p);           // i, o
            gs[par][g][lane] = act;
        }
        __syncthreads();   // the ONLY barrier per step
        if (g < 4) {
            // ---- phase 2: replicated cell update (identical in waves 0-3) ----
            const float i_ = gs[par][0][lane], j_ = gs[par][1][lane];
            const float f_ = gs[par][2][lane], o_ = gs[par][3][lane];
            c1 = fmaf(c1, f_, i_ * j_);
            h1 = ftanh(c1) * o_;
            // layer-2 dot for gate g (off the critical path)
            float pd = wave_sum64(h1 * w2g);
            if (lane == 63) dbuf[par][g] = pd;
        } else if (t > 0 && lane == 0) {
            // ---- wave 4: layer-2 recurrence for step t-1 ----
            const int pp = par ^ 1;
            const float d0 = dbuf[pp][0], d1 = dbuf[pp][1];
            const float d2 = dbuf[pp][2], d3 = dbuf[pp][3];
            const float i2 = fsig (fmaf(h2, w2h0, d0) + b20);
            const float j2 = ftanh(fmaf(h2, w2h1, d1) + b21);
            const float f2 = fsig (fmaf(h2, w2h2, d2) + b22 + 1.f);
            const float o2 = fsig (fmaf(h2, w2h3, d3) + b23);
            c2 = fmaf(c2, f2, i2 * j2);
            h2 = ftanh(c2) * o2;
            yrow[t - 1] = h2;
        }
    }
    __syncthreads();
    if (g == 4 && lane == 0) {   // final layer-2 step (t = TT-1)
        const int pp = (TT - 1) & 1;
        const float d0 = dbuf[pp][0], d1 = dbuf[pp][1];
        const float d2 = dbuf[pp][2], d3 = dbuf[pp][3];
        const float i2 = fsig (fmaf(h2, w2h0, d0) + b20);
        const float j2 = ftanh(fmaf(h2, w2h1, d1) + b21);
        const float f2 = fsig (fmaf(h2, w2h2, d2) + b22 + 1.f);
        const float o2 = fsig (fmaf(h2, w2h3, d3) + b23);
        c2 = fmaf(c2, f2, i2 * j2);
        h2 = ftanh(c2) * o2;
        yrow[TT - 1] = h2;
    }
}

extern "C" void kernel_launch(void* const* d_in, const int* in_sizes, int n_in,
                              void* d_out, int out_size, void* d_ws, size_t ws_size,
                              hipStream_t stream) {
    const float* x  = (const float*)d_in[0];
    const float* W1 = (const float*)d_in[1];
    const float* b1 = (const float*)d_in[2];
    const float* W2 = (const float*)d_in[3];
    const float* b2 = (const float*)d_in[4];
    float* y = (float*)d_out;
    lstm2_kernel<<<512, 320, 0, stream>>>(x, W1, b1, W2, b2, y);
}